// Round 7
// baseline (78665.662 us; speedup 1.0000x reference)
//
#include <hip/hip_runtime.h>
#include <stdint.h>

#define TT 8192
#define NN 512
#define MM 2048
#define KK 3
#define RHO_C 1e-4f
#define NWG 256
#define NTHR 512

typedef unsigned int u32x2 __attribute__((ext_vector_type(2)));
typedef unsigned int u32x4 __attribute__((ext_vector_type(4)));

// Persistent kernel: one WG per CU, WG wg owns rows [8*wg, 8*wg+8).
// Wave w owns row 8*wg+w; lane holds M cols c = lane + 64*cb (cb<32) in regs.
//
// Protocol (parity/epoch-tag, same induction as R1/R5/R6, re-verified for 8B):
//   record hrec[parity][row] = 8B {f32 val, u32 tag}, stored by the owning
//   wave's lane 0 with global_store_dwordx2 sc0 sc1 IMMEDIATELY after the
//   reduce (before B1 -- visibility overlaps the barrier). 8B aligned store
//   is a single transaction (no tear). Store of epoch e overwrites e-2's
//   record; safe because our poll-for-(e-1) succeeded => every WG published
//   e-1 => every WG finished consuming e-2. During poll-for-e a record's tag
//   is in {e-2, e}; ws poison 0xAAAAAAAA never matches a real tag.
//   B1 (post-compute) orders all lds_h/lds_x reads before the poll's lds_h
//   overwrites; B2 (post-poll) orders them before the next compute.
// R7 changes vs R6: per-wave pre-B1 publish (no LDS funnel on the visibility
//   path); ok-flag poll (each lds_h row written exactly once -- kills the
//   1.6e9 idempotent-rewrite bank conflicts); x_{t+1} loaded into a register
//   at k==1 and ds_written after k==2's B1 (HBM latency hidden under a hop);
//   dead final publish/poll skipped.
__global__ __launch_bounds__(NTHR, 2)
void lista_persist(const float* __restrict__ x,      // [T, N]
                   const float* __restrict__ A,      // [K, M, N]
                   const float* __restrict__ alpha,  // [K+1]
                   const float* __restrict__ h0,     // [M]
                   float* __restrict__ out,          // [T, M]
                   unsigned long long* __restrict__ hbuf) // ws: [2][MM] 8B recs
{
    const int wg   = blockIdx.x;
    const int tid  = threadIdx.x;
    const int w    = tid >> 6;
    const int lane = tid & 63;
    const int row  = wg * 8 + w;

    __shared__ float At[4][MM];      // 32 KB (init only)
    __shared__ float Aplds[8][NN];   // 16 KB (init only)
    __shared__ float lds_h[MM];      //  8 KB
    __shared__ float lds_x[NN];      //  2 KB

    float inva[KK], rhoa[KK];
#pragma unroll
    for (int k = 0; k < KK; ++k) {
        float a = alpha[k + 1];
        inva[k] = 1.0f / a;
        rhoa[k] = RHO_C / a;
    }

    // A'_k row of this wave in regs: a2[k][m] = A[k][row][lane+64m] / a_k
    float a2[KK][8];
#pragma unroll
    for (int k = 0; k < KK; ++k) {
        const float* Ar = A + ((size_t)k * MM + row) * NN;
#pragma unroll
        for (int m = 0; m < 8; ++m) a2[k][m] = Ar[lane + 64 * m] * inva[k];
    }

    // ---------------- init: M_k = I - (A_k A_k^T)/a_k rows into registers ----
    float mr[KK][32];
#pragma unroll
    for (int k = 0; k < KK; ++k)
#pragma unroll
        for (int cb = 0; cb < 32; ++cb) mr[k][cb] = 0.0f;

#pragma unroll
    for (int k = 0; k < KK; ++k) {
#pragma unroll
        for (int m = 0; m < 8; ++m) Aplds[w][lane + 64 * m] = a2[k][m];
        const float* Ak = A + (size_t)k * MM * NN;
        for (int jc = 0; jc < 128; ++jc) {
            __syncthreads();
#pragma unroll
            for (int cc = 0; cc < 4; ++cc) {
                int c = tid + 512 * cc;
                const float4 v = *(const float4*)(Ak + (size_t)c * NN + jc * 4);
                At[0][c] = v.x; At[1][c] = v.y; At[2][c] = v.z; At[3][c] = v.w;
            }
            __syncthreads();
#pragma unroll
            for (int jj = 0; jj < 4; ++jj) {
                float s = Aplds[w][jc * 4 + jj];   // broadcast
#pragma unroll
                for (int cb = 0; cb < 32; ++cb)
                    mr[k][cb] += s * At[jj][lane + 64 * cb];
            }
        }
        __syncthreads();
    }
#pragma unroll
    for (int k = 0; k < KK; ++k)
#pragma unroll
        for (int cb = 0; cb < 32; ++cb) {
            float d = (lane + 64 * cb == row) ? 1.0f : 0.0f;
            mr[k][cb] = d - mr[k][cb];
        }

    // consumer ownership: thread tid polls 16B pairs at indices tid and
    // tid+512 of the active parity buffer; pair p covers rows {2p, 2p+1}.
    const int rA0 = 2 * tid,        rA1 = rA0 + 1;
    const int rB0 = 2 * tid + 1024, rB1 = rB0 + 1;

    // ---------------- prologue: epoch-0 state straight from inputs ----------
#pragma unroll
    for (int j = 0; j < 4; ++j) lds_h[tid + 512 * j] = h0[tid + 512 * j];
    lds_x[tid] = x[tid];
    __syncthreads();

    // ---------------- sequential scan ----------------
    unsigned int e = 0;   // epoch of the state in lds_h
    float xv = 0.0f;      // x_{t+1} staged in a register across one hop
    for (int t = 0; t < TT; ++t) {
#pragma unroll
        for (int k = 0; k < KK; ++k) {
            // --- compute: v = M_k[row,:] @ h + (A_k[row,:]/a) @ x_t ---
            float p = 0.0f;
#pragma unroll
            for (int m = 0; m < 8; ++m)  p += a2[k][m] * lds_x[lane + 64 * m];
#pragma unroll
            for (int cb = 0; cb < 32; ++cb) p += mr[k][cb] * lds_h[lane + 64 * cb];
#pragma unroll
            for (int s = 1; s < 64; s <<= 1) p += __shfl_xor(p, s, 64);
            float hn = fmaxf(p - rhoa[k], 0.0f);

            // --- publish epoch e+1 immediately (pre-B1): visibility overlaps
            //     the barrier + everyone's poll startup ---
            ++e;
            if (lane == 0) {
                u32x2 rec; rec.x = __float_as_uint(hn); rec.y = e;
                unsigned long long* dst = hbuf + (size_t)(e & 1) * MM + row;
                asm volatile("global_store_dwordx2 %0, %1, off sc0 sc1"
                             :: "v"(dst), "v"(rec) : "memory");
                if (k == KK - 1) out[(size_t)t * MM + row] = hn;
            }
            // hoisted x_{t+1} load: register-carried from k==1 to k==2
            if (k == 1 && t + 1 < TT) xv = x[(size_t)(t + 1) * NN + tid];

            if (k == KK - 1 && t == TT - 1) break;   // nobody polls the last epoch

            __syncthreads();   // B1: all lds_h/lds_x reads of epoch-e-1 state done
            if (k == KK - 1) lds_x[tid] = xv;        // latency long hidden

            // --- poll for state e: free-running, ok-flagged, wave-local exit ---
            const u32x4* src = (const u32x4*)(hbuf + (size_t)(e & 1) * MM);
            const u32x4* pA = src + tid;
            const u32x4* pB = src + tid + 512;
            bool a0 = false, a1 = false, b0 = false, b1 = false;
            bool done = false;
            do {
                u32x4 ra, rb;
                asm volatile(
                    "global_load_dwordx4 %0, %2, off sc0 sc1\n\t"
                    "global_load_dwordx4 %1, %3, off sc0 sc1\n\t"
                    "s_waitcnt vmcnt(0)"
                    : "=v"(ra), "=v"(rb)
                    : "v"(pA), "v"(pB)
                    : "memory");
                if (!a0 && ra.y == e) { lds_h[rA0] = __uint_as_float(ra.x); a0 = true; }
                if (!a1 && ra.w == e) { lds_h[rA1] = __uint_as_float(ra.z); a1 = true; }
                if (!b0 && rb.y == e) { lds_h[rB0] = __uint_as_float(rb.x); b0 = true; }
                if (!b1 && rb.w == e) { lds_h[rB1] = __uint_as_float(rb.z); b1 = true; }
                done = __all((int)(a0 & a1 & b0 & b1));   // wave-local, no barrier
            } while (!done);
            __syncthreads();   // B2: all waves' rows landed in lds_h; lds_x ready
        }
    }
}

extern "C" void kernel_launch(void* const* d_in, const int* in_sizes, int n_in,
                              void* d_out, int out_size, void* d_ws, size_t ws_size,
                              hipStream_t stream) {
    const float* x     = (const float*)d_in[0];
    const float* A     = (const float*)d_in[1];
    const float* alpha = (const float*)d_in[2];
    const float* h0    = (const float*)d_in[3];
    float* out = (float*)d_out;
    unsigned long long* hbuf = (unsigned long long*)d_ws;   // 2*2048*8 = 32 KB

    hipLaunchKernelGGL(lista_persist, dim3(NWG), dim3(NTHR), 0, stream,
                       x, A, alpha, h0, out, hbuf);
}